// Round 6
// baseline (1059.967 us; speedup 1.0000x reference)
//
#include <hip/hip_runtime.h>

#define T_DIM 512
#define B_DIM 64
#define I_DIM 1024
#define H_DIM 1024
#define G3    3072                 // 3*H
#define M_DIM (T_DIM * B_DIM)      // 32768
#define K_DIM 1024
#define KT    16                   // K_DIM / 64

typedef unsigned short u16;
typedef __bf16 bf16x8 __attribute__((ext_vector_type(8)));
typedef float  f32x4  __attribute__((ext_vector_type(4)));
typedef unsigned short u16x8 __attribute__((ext_vector_type(8)));

__device__ __forceinline__ u16 f2bf(float x) {
  union { float f; unsigned u; } v; v.f = x;
  unsigned r = v.u + 0x7fffu + ((v.u >> 16) & 1u);   // RNE
  return (u16)(r >> 16);
}
__device__ __forceinline__ float bf2f(u16 x) {
  union { unsigned u; float f; } v; v.u = ((unsigned)x) << 16;
  return v.f;
}

// ---------------- cast x: f32 -> bf16, 8 elems/thread ----------------
__global__ void cast_f32_to_bf16_kernel(const float* __restrict__ in,
                                        u16* __restrict__ out, int n8) {
  int idx = blockIdx.x * blockDim.x + threadIdx.x;
  int stride = gridDim.x * blockDim.x;
  for (int i = idx; i < n8; i += stride) {
    const float4* p = (const float4*)in + 2 * (size_t)i;
    float4 a = p[0], b = p[1];
    u16x8 o;
    o[0] = f2bf(a.x); o[1] = f2bf(a.y); o[2] = f2bf(a.z); o[3] = f2bf(a.w);
    o[4] = f2bf(b.x); o[5] = f2bf(b.y); o[6] = f2bf(b.z); o[7] = f2bf(b.w);
    *((u16x8*)out + i) = o;
  }
}

// ------------- transpose-cast W[K][N] f32 -> Wt[N][K] bf16 -------------
__global__ void transpose_cast_kernel(const float* __restrict__ W,
                                      u16* __restrict__ Wt, int K, int N) {
  __shared__ float tile[32][33];
  int n0 = blockIdx.x * 32, k0 = blockIdx.y * 32;
  int tx = threadIdx.x, ty = threadIdx.y;   // blockDim = (32,8)
  #pragma unroll
  for (int dy = 0; dy < 32; dy += 8)
    tile[ty + dy][tx] = W[(size_t)(k0 + ty + dy) * N + n0 + tx];
  __syncthreads();
  #pragma unroll
  for (int dy = 0; dy < 32; dy += 8)
    Wt[(size_t)(n0 + ty + dy) * K + k0 + tx] = f2bf(tile[tx][ty + dy]);
}

// === 256x256 GEMM, 2 barriers/K-tile, every MFMA quadrant shadows reads ===
__device__ __forceinline__ void gload_lds16(const void* g, void* l) {
  __builtin_amdgcn_global_load_lds(
      (const __attribute__((address_space(1))) void*)g,
      (__attribute__((address_space(3))) void*)l, 16, 0, 0);
}

// stage one half-tile (128 rows x 64 k), rows [rb, rb+128) at k0 into lbuf
// (linear [256][64] u16). Source pre-swizzled: LDS[row][c] = G[row][c ^ (row&7)].
__device__ __forceinline__ void stage_half(const u16* __restrict__ G, u16* lbuf,
                                           int rb, int k0, int w, int l) {
  const int cs   = (l & 7) ^ (l >> 3);   // source chunk for this lane
  const int rsub = l >> 3;
  #pragma unroll
  for (int r = 0; r < 2; ++r) {
    const int row0 = rb + r * 64 + w * 8;           // wave-uniform row base (mult of 8)
    gload_lds16(G + (size_t)(row0 + rsub) * K_DIM + k0 + cs * 8,
                lbuf + (size_t)row0 * 64);
  }
}

// read one MFMA fragment; row = (mult of 16) + fr so row&7 == fr&7
__device__ __forceinline__ bf16x8 ldfrag(const u16* buf, int row, int ks, int fr, int g4) {
  const int slot = ((ks << 2) + g4) ^ (fr & 7);
  return *(const bf16x8*)(buf + (size_t)row * 64 + slot * 8);
}

__device__ __forceinline__ void read_a(const u16* buf, bf16x8 (&dst)[4][2],
                                       int rbase, int fr, int g4) {
  #pragma unroll
  for (int m = 0; m < 4; ++m) {
    dst[m][0] = ldfrag(buf, rbase + m * 16 + fr, 0, fr, g4);
    dst[m][1] = ldfrag(buf, rbase + m * 16 + fr, 1, fr, g4);
  }
}
__device__ __forceinline__ void read_b(const u16* buf, bf16x8 (&dst)[2][2],
                                       int rbase, int fr, int g4) {
  #pragma unroll
  for (int n = 0; n < 2; ++n) {
    dst[n][0] = ldfrag(buf, rbase + n * 16 + fr, 0, fr, g4);
    dst[n][1] = ldfrag(buf, rbase + n * 16 + fr, 1, fr, g4);
  }
}

template <int MO, int NO>
__device__ __forceinline__ void mfma_q(f32x4 (&acc)[8][4],
                                       const bf16x8 (&av)[4][2],
                                       const bf16x8 (&bv)[2][2]) {
  __builtin_amdgcn_s_setprio(1);
  #pragma unroll
  for (int m = 0; m < 4; ++m)
    #pragma unroll
    for (int n = 0; n < 2; ++n) {
      acc[MO + m][NO + n] = __builtin_amdgcn_mfma_f32_16x16x32_bf16(
          av[m][0], bv[n][0], acc[MO + m][NO + n], 0, 0, 0);
      acc[MO + m][NO + n] = __builtin_amdgcn_mfma_f32_16x16x32_bf16(
          av[m][1], bv[n][1], acc[MO + m][NO + n], 0, 0, 0);
    }
  __builtin_amdgcn_s_setprio(0);
}

#define BARRIER()  do { __builtin_amdgcn_s_barrier(); __builtin_amdgcn_sched_barrier(0); } while (0)
#define LGKM0()    do { asm volatile("s_waitcnt lgkmcnt(0)" ::: "memory"); __builtin_amdgcn_sched_barrier(0); } while (0)
#define SCHED0()   __builtin_amdgcn_sched_barrier(0)

// One K-tile. Entry: av0 = A(T) m0-3, BV0 = B(T) n0-1 reads ISSUED (not waited);
// tile T resident+synced. Exit: av0 = A(T+1) m0-3, BV1 = B(T+1) n0-1 issued.
// BV0/BV1 physical roles alternate per tile (2-coloring).
#define ITER(BV0, BV1, T, ST2)                                               \
  {                                                                          \
    const u16* Ac = As[(T) & 1];                                             \
    const u16* Bc = Bs[(T) & 1];                                             \
    /* W0: Q0 = av0 x BV0 ; shadow: stage Bhi(T+1), read BV1 <- B(T) n2-3 */ \
    LGKM0();                                                                 \
    stage_half(Bb, Bs[((T) + 1) & 1], 128, ((T) + 1) * 64, w, l);            \
    read_b(Bc, BV1, wn * 64 + 32, fr, g4);                                   \
    SCHED0();                                                                \
    mfma_q<0, 0>(acc, av0, BV0);                                             \
    /* W1: Q1 = av0 x BV1 ; shadow: read av1 <- A(T) m4-7 */                 \
    LGKM0();                                                                 \
    read_a(Ac, av1, wm * 128 + 64, fr, g4);                                  \
    SCHED0();                                                                \
    mfma_q<0, 2>(acc, av0, BV1);                                             \
    /* W2: Q2 = av1 x BV1 ; all tile-T LDS reads done -> stage T+2 */        \
    LGKM0();                                                                 \
    BARRIER();                                                               \
    if (ST2) {                                                               \
      stage_half(Ab, As[(T) & 1], 0,   ((T) + 2) * 64, w, l);                \
      stage_half(Ab, As[(T) & 1], 128, ((T) + 2) * 64, w, l);                \
    }                                                                        \
    SCHED0();                                                                \
    mfma_q<4, 2>(acc, av1, BV1);                                             \
    if (ST2) { asm volatile("s_waitcnt vmcnt(4)" ::: "memory"); }            \
    else     { asm volatile("s_waitcnt vmcnt(0)" ::: "memory"); }            \
    BARRIER();                     /* tile T+1 fully resident everywhere */  \
    /* W3: Q3 = av1 x BV0 ; shadow: read next av0', BV1<-B(T+1) n0-1 */      \
    read_a(As[((T) + 1) & 1], av0, wm * 128, fr, g4);                        \
    read_b(Bs[((T) + 1) & 1], BV1, wn * 64, fr, g4);                         \
    if (ST2) stage_half(Bb, Bs[(T) & 1], 0, ((T) + 2) * 64, w, l);           \
    SCHED0();                                                                \
    mfma_q<4, 0>(acc, av1, BV0);                                             \
  }

__global__ __launch_bounds__(512, 2) void gemm256_kernel(
    const u16* __restrict__ A, const u16* __restrict__ Bt,
    const float* __restrict__ bias, u16* __restrict__ C, int N) {
  __shared__ u16 As[2][256 * 64];
  __shared__ u16 Bs[2][256 * 64];
  const int tid = threadIdx.x;
  const int l  = tid & 63, w = tid >> 6;
  const int wm = w >> 2,  wn = w & 3;
  const int fr = l & 15,  g4 = l >> 4;

  // T1: bijective XCD swizzle (nwg = 1536, divisible by 8)
  const int lin = blockIdx.y * gridDim.x + blockIdx.x;
  const int cpx = (gridDim.x * gridDim.y) >> 3;
  const int swz = (lin & 7) * cpx + (lin >> 3);
  const int bx = swz % gridDim.x, by = swz / gridDim.x;
  const int bm = by * 256, bn = bx * 256;

  const u16* Ab = A  + (size_t)bm * K_DIM;
  const u16* Bb = Bt + (size_t)bn * K_DIM;

  // prologue: tile0 fully + tile1 {A-lo, A-hi, B-lo}  (14 loads/thread)
  stage_half(Ab, As[0], 0,   0,  w, l);
  stage_half(Ab, As[0], 128, 0,  w, l);
  stage_half(Bb, Bs[0], 0,   0,  w, l);
  stage_half(Bb, Bs[0], 128, 0,  w, l);
  stage_half(Ab, As[1], 0,   64, w, l);
  stage_half(Ab, As[1], 128, 64, w, l);
  stage_half(Bb, Bs[1], 0,   64, w, l);

  f32x4 acc[8][4] = {};
  bf16x8 av0[4][2], av1[4][2], bvA[2][2], bvB[2][2];

  asm volatile("s_waitcnt vmcnt(6)" ::: "memory");   // tile0 resident
  BARRIER();
  read_a(As[0], av0, wm * 128, fr, g4);              // issue tile0 Q0 frags
  read_b(Bs[0], bvA, wn * 64, fr, g4);
  SCHED0();

  #pragma unroll 1
  for (int t2 = 0; t2 < (KT - 2) / 2; ++t2) {        // T = 0..13
    const int T = 2 * t2;
    ITER(bvA, bvB, T,     true);
    ITER(bvB, bvA, T + 1, true);
  }
  ITER(bvA, bvB, KT - 2, false);                     // T=14: vmcnt(0), no T+2

  // peeled tile KT-1 = 15 (odd: bv0 role = bvB)
  {
    const u16* Ac = As[1];
    const u16* Bc = Bs[1];
    LGKM0();
    read_b(Bc, bvA, wn * 64 + 32, fr, g4);
    SCHED0();
    mfma_q<0, 0>(acc, av0, bvB);
    LGKM0();
    read_a(Ac, av1, wm * 128 + 64, fr, g4);
    SCHED0();
    mfma_q<0, 2>(acc, av0, bvA);
    LGKM0();
    mfma_q<4, 2>(acc, av1, bvA);
    mfma_q<4, 0>(acc, av1, bvB);
    BARRIER();                     // all LDS reads done -> LDS reusable
  }

  // ---- epilogue: per-wave LDS bounce -> fully coalesced 16B stores ----
  float bb[4];
  #pragma unroll
  for (int j = 0; j < 4; ++j) bb[j] = bias[bn + wn * 64 + j * 16 + fr];

  u16* eb = (w < 4) ? ((u16*)As + (size_t)w * 8192)
                    : ((u16*)Bs + (size_t)(w - 4) * 8192);   // private 128x64 region
  #pragma unroll
  for (int i = 0; i < 8; ++i)
    #pragma unroll
    for (int j = 0; j < 4; ++j)
      #pragma unroll
      for (int v = 0; v < 4; ++v) {
        const int row = i * 16 + g4 * 4 + v;
        const int col = j * 16 + fr;
        eb[row * 64 + (col ^ ((row & 12) << 2))] = f2bf(acc[i][j][v] + bb[j]);
      }
  LGKM0();                            // own-wave ds_writes visible (private region)
  #pragma unroll
  for (int c = 0; c < 16; ++c) {
    const int lrow = c * 8 + (l >> 3);
    const int lcol = (l & 7) * 8;
    u16x8 d = *(const u16x8*)&eb[lrow * 64 + (lcol ^ ((lrow & 12) << 2))];
    *(u16x8*)&C[(size_t)(bm + wm * 128 + lrow) * N + (bn + wn * 64 + lcol)] = d;
  }
}

// ---------------- scan: elementwise recurrence over t ----------------
template <int OUT_BF16>
__global__ void scan_kernel(const u16* __restrict__ gates,   // [T*B][3H] bf16
                            const float* __restrict__ h0,    // [B][H]
                            const int* __restrict__ L,       // [B]
                            u16* __restrict__ out_bf,        // [T*B][H] bf16
                            float* __restrict__ out_f,       // [T*B][H] f32
                            float* __restrict__ hlast) {     // [B][H]
  const int e = blockIdx.x * blockDim.x + threadIdx.x;       // 0..B*H-1
  const int b = e >> 10;
  const int j = e & 1023;
  float h = h0[e];
  const int Lb = L[b];
  const size_t g0 = (size_t)b * G3 + j;
  const size_t o0 = (size_t)b * H_DIM + j;
  int t = 0;
  #pragma unroll 8
  for (; t < Lb; ++t) {
    const size_t gt = g0 + (size_t)t * (B_DIM * G3);
    float p = bf2f(gates[gt]);
    float q = bf2f(gates[gt + H_DIM]);
    float r = bf2f(gates[gt + 2 * H_DIM]);
    float ii = 1.f / (1.f + __expf(-(p + h)));
    float ff = 1.f / (1.f + __expf(-(q - h)));
    float u  = ii * r + ff * h;
    float e2 = __expf(2.f * u);
    h = 1.f - 2.f / (e2 + 1.f);                 // tanh(u)
    if (OUT_BF16) out_bf[o0 + (size_t)t * (B_DIM * H_DIM)] = f2bf(h);
    else          out_f [o0 + (size_t)t * (B_DIM * H_DIM)] = h;
  }
  const u16 hb = f2bf(h);
  for (; t < T_DIM; ++t) {                      // frozen tail: stores only
    if (OUT_BF16) out_bf[o0 + (size_t)t * (B_DIM * H_DIM)] = hb;
    else          out_f [o0 + (size_t)t * (B_DIM * H_DIM)] = h;
  }
  hlast[o0] = h;
}

extern "C" void kernel_launch(void* const* d_in, const int* in_sizes, int n_in,
                              void* d_out, int out_size, void* d_ws, size_t ws_size,
                              hipStream_t stream) {
  const float* x  = (const float*)d_in[0];
  const float* h0 = (const float*)d_in[1];
  const float* W1 = (const float*)d_in[2];
  const float* b1 = (const float*)d_in[3];
  const float* W2 = (const float*)d_in[4];
  const float* b2 = (const float*)d_in[5];
  const int*   L  = (const int*)d_in[6];

  float* out2 = (float*)d_out;                         // [T][B][H]
  float* hl   = out2 + (size_t)T_DIM * B_DIM * H_DIM;  // h1 [B][H], then h2

  // workspace layout
  char* w = (char*)d_ws;
  u16* xb    = (u16*)(w);                            //  64 MB  x bf16
  u16* W1t   = (u16*)(w + (size_t)67108864);         //   6 MB  W1^T bf16
  u16* W2t   = (u16*)(w + (size_t)73400320);         //   6 MB  W2^T bf16
  u16* gates = (u16*)(w + (size_t)79691776);         // 192 MB  gates bf16 (reused)
  u16* out1  = (u16*)(w + (size_t)281018368);        //  64 MB  out1 bf16

  cast_f32_to_bf16_kernel<<<2048, 256, 0, stream>>>(x, xb, (T_DIM * B_DIM * I_DIM) / 8);
  dim3 tb(32, 8);
  transpose_cast_kernel<<<dim3(G3 / 32, I_DIM / 32), tb, 0, stream>>>(W1, W1t, I_DIM, G3);
  transpose_cast_kernel<<<dim3(G3 / 32, H_DIM / 32), tb, 0, stream>>>(W2, W2t, H_DIM, G3);

  // layer 1
  gemm256_kernel<<<dim3(G3 / 256, M_DIM / 256), 512, 0, stream>>>(
      xb, W1t, b1, gates, G3);
  scan_kernel<1><<<(B_DIM * H_DIM) / 256, 256, 0, stream>>>(
      gates, h0, L, out1, nullptr, hl);

  // layer 2
  gemm256_kernel<<<dim3(G3 / 256, M_DIM / 256), 512, 0, stream>>>(
      out1, W2t, b2, gates, G3);
  scan_kernel<0><<<(B_DIM * H_DIM) / 256, 256, 0, stream>>>(
      gates, h0 + B_DIM * H_DIM, L, nullptr, out2, hl + B_DIM * H_DIM);
}

// Round 7
// 727.497 us; speedup vs baseline: 1.4570x; 1.4570x over previous
//
#include <hip/hip_runtime.h>

#define T_DIM 512
#define B_DIM 64
#define I_DIM 1024
#define H_DIM 1024
#define G3    3072                 // 3*H
#define M_DIM (T_DIM * B_DIM)      // 32768
#define K_DIM 1024
#define KT    16                   // K_DIM / 64

typedef unsigned short u16;
typedef __bf16 bf16x8 __attribute__((ext_vector_type(8)));
typedef float  f32x4  __attribute__((ext_vector_type(4)));
typedef unsigned short u16x8 __attribute__((ext_vector_type(8)));

__device__ __forceinline__ u16 f2bf(float x) {
  union { float f; unsigned u; } v; v.f = x;
  unsigned r = v.u + 0x7fffu + ((v.u >> 16) & 1u);   // RNE
  return (u16)(r >> 16);
}
__device__ __forceinline__ float bf2f(u16 x) {
  union { unsigned u; float f; } v; v.u = ((unsigned)x) << 16;
  return v.f;
}

// ---------------- cast x: f32 -> bf16, 8 elems/thread ----------------
__global__ void cast_f32_to_bf16_kernel(const float* __restrict__ in,
                                        u16* __restrict__ out, int n8) {
  int idx = blockIdx.x * blockDim.x + threadIdx.x;
  int stride = gridDim.x * blockDim.x;
  for (int i = idx; i < n8; i += stride) {
    const float4* p = (const float4*)in + 2 * (size_t)i;
    float4 a = p[0], b = p[1];
    u16x8 o;
    o[0] = f2bf(a.x); o[1] = f2bf(a.y); o[2] = f2bf(a.z); o[3] = f2bf(a.w);
    o[4] = f2bf(b.x); o[5] = f2bf(b.y); o[6] = f2bf(b.z); o[7] = f2bf(b.w);
    *((u16x8*)out + i) = o;
  }
}

// ------------- transpose-cast W[K][N] f32 -> Wt[N][K] bf16 -------------
__global__ void transpose_cast_kernel(const float* __restrict__ W,
                                      u16* __restrict__ Wt, int K, int N) {
  __shared__ float tile[32][33];
  int n0 = blockIdx.x * 32, k0 = blockIdx.y * 32;
  int tx = threadIdx.x, ty = threadIdx.y;   // blockDim = (32,8)
  #pragma unroll
  for (int dy = 0; dy < 32; dy += 8)
    tile[ty + dy][tx] = W[(size_t)(k0 + ty + dy) * N + n0 + tx];
  __syncthreads();
  #pragma unroll
  for (int dy = 0; dy < 32; dy += 8)
    Wt[(size_t)(n0 + ty + dy) * K + k0 + tx] = f2bf(tile[tx][ty + dy]);
}

// ========== 256x256 GEMM, m201-faithful 8-phase schedule ==========
// 8 waves (2M x 4N), BK=64, 2 LDS K-tile buffers. Per K-tile: 4 phases, each
// {ds-reads; 1 half-tile stage; barrier; lgkm0; setprio+16 MFMA; barrier};
// counted vmcnt(4) once per tile at the last phase. Tile T stages B(T+1) at
// P0/P1 (other buffer) and A(T+2) at P2/P3 (own buffer, >=2 barriers after
// tile T's last A-read).
__device__ __forceinline__ void gload_lds16(const void* g, void* l) {
  __builtin_amdgcn_global_load_lds(
      (const __attribute__((address_space(1))) void*)g,
      (__attribute__((address_space(3))) void*)l, 16, 0, 0);
}

// stage one half-tile (128 rows x 64 k), rows [rb, rb+128) at k0 into lbuf
// (linear [256][64] u16). Source pre-swizzled: LDS[row][c] = G[row][c ^ (row&7)].
__device__ __forceinline__ void stage_half(const u16* __restrict__ G, u16* lbuf,
                                           int rb, int k0, int w, int l) {
  const int cs   = (l & 7) ^ (l >> 3);   // source chunk for this lane
  const int rsub = l >> 3;
  #pragma unroll
  for (int r = 0; r < 2; ++r) {
    const int row0 = rb + r * 64 + w * 8;           // wave-uniform row base (mult of 8)
    gload_lds16(G + (size_t)(row0 + rsub) * K_DIM + k0 + cs * 8,
                lbuf + (size_t)row0 * 64);
  }
}

// read one MFMA fragment; row = (mult of 16) + fr so row&7 == fr&7
__device__ __forceinline__ bf16x8 ldfrag(const u16* buf, int row, int ks, int fr, int g4) {
  const int slot = ((ks << 2) + g4) ^ (fr & 7);
  return *(const bf16x8*)(buf + (size_t)row * 64 + slot * 8);
}

__device__ __forceinline__ void read_a(const u16* buf, bf16x8 (&dst)[4][2],
                                       int rbase, int fr, int g4) {
  #pragma unroll
  for (int m = 0; m < 4; ++m) {
    dst[m][0] = ldfrag(buf, rbase + m * 16 + fr, 0, fr, g4);
    dst[m][1] = ldfrag(buf, rbase + m * 16 + fr, 1, fr, g4);
  }
}
__device__ __forceinline__ void read_b(const u16* buf, bf16x8 (&dst)[2][2],
                                       int rbase, int fr, int g4) {
  #pragma unroll
  for (int n = 0; n < 2; ++n) {
    dst[n][0] = ldfrag(buf, rbase + n * 16 + fr, 0, fr, g4);
    dst[n][1] = ldfrag(buf, rbase + n * 16 + fr, 1, fr, g4);
  }
}

template <int MO, int NO>
__device__ __forceinline__ void mfma_q(f32x4 (&acc)[8][4],
                                       const bf16x8 (&av)[4][2],
                                       const bf16x8 (&bv)[2][2]) {
  __builtin_amdgcn_s_setprio(1);
  #pragma unroll
  for (int ks = 0; ks < 2; ++ks)          // ks-outer: 8 independent MFMAs per pass
    #pragma unroll
    for (int m = 0; m < 4; ++m)
      #pragma unroll
      for (int n = 0; n < 2; ++n)
        acc[MO + m][NO + n] = __builtin_amdgcn_mfma_f32_16x16x32_bf16(
            av[m][ks], bv[n][ks], acc[MO + m][NO + n], 0, 0, 0);
  __builtin_amdgcn_s_setprio(0);
}

#define BARRIER()  do { __builtin_amdgcn_s_barrier(); __builtin_amdgcn_sched_barrier(0); } while (0)
#define LGKM0()    do { asm volatile("s_waitcnt lgkmcnt(0)" ::: "memory"); __builtin_amdgcn_sched_barrier(0); } while (0)

__global__ __launch_bounds__(512, 2) void gemm256_kernel(
    const u16* __restrict__ A, const u16* __restrict__ Bt,
    const float* __restrict__ bias, u16* __restrict__ C, int N) {
  __shared__ u16 As[2][256 * 64];
  __shared__ u16 Bs[2][256 * 64];
  const int tid = threadIdx.x;
  const int l  = tid & 63, w = tid >> 6;
  const int wm = w >> 2,  wn = w & 3;
  const int fr = l & 15,  g4 = l >> 4;

  // T1: bijective XCD swizzle (nwg = 1536, divisible by 8)
  const int lin = blockIdx.y * gridDim.x + blockIdx.x;
  const int cpx = (gridDim.x * gridDim.y) >> 3;
  const int swz = (lin & 7) * cpx + (lin >> 3);
  const int bx = swz % gridDim.x, by = swz / gridDim.x;
  const int bm = by * 256, bn = bx * 256;

  const u16* Ab = A  + (size_t)bm * K_DIM;
  const u16* Bb = Bt + (size_t)bn * K_DIM;

  // prologue: tile0 all 4 halves + {Alo, Ahi}(tile1)  (12 loads/thread)
  stage_half(Ab, As[0], 0,   0,  w, l);
  stage_half(Ab, As[0], 128, 0,  w, l);
  stage_half(Bb, Bs[0], 0,   0,  w, l);
  stage_half(Bb, Bs[0], 128, 0,  w, l);
  stage_half(Ab, As[1], 0,   64, w, l);
  stage_half(Ab, As[1], 128, 64, w, l);

  f32x4 acc[8][4] = {};
  bf16x8 av0[4][2], av1[4][2], bv0[2][2], bv1[2][2];

  asm volatile("s_waitcnt vmcnt(4)" ::: "memory");   // tile0 resident, A(1) in flight
  BARRIER();

  #pragma unroll 2
  for (int T = 0; T < KT; ++T) {
    const int cur = T & 1;
    const u16* Ac = As[cur];
    const u16* Bc = Bs[cur];
    const int k1 = (T + 1) * 64, k2 = (T + 2) * 64;
    const bool st1 = (T + 1) < KT;
    const bool st2 = (T + 2) < KT;

    // ---- P0: read av0 + bv0 (12); stage Blo(T+1); Q0 = av0 x bv0 ----
    read_a(Ac, av0, wm * 128, fr, g4);
    read_b(Bc, bv0, wn * 64, fr, g4);
    if (st1) stage_half(Bb, Bs[cur ^ 1], 0, k1, w, l);
    asm volatile("s_waitcnt lgkmcnt(8)" ::: "memory");   // smooth the 12-read burst
    BARRIER();
    LGKM0();
    mfma_q<0, 0>(acc, av0, bv0);
    BARRIER();

    // ---- P1: read av1 (8); stage Bhi(T+1); Q1 = av1 x bv0 ----
    read_a(Ac, av1, wm * 128 + 64, fr, g4);
    if (st1) stage_half(Bb, Bs[cur ^ 1], 128, k1, w, l);
    BARRIER();
    LGKM0();
    mfma_q<4, 0>(acc, av1, bv0);
    BARRIER();

    // ---- P2: read bv1 (4); stage Alo(T+2) (own buf, A-reads done); Q2 ----
    read_b(Bc, bv1, wn * 64 + 32, fr, g4);
    if (st2) stage_half(Ab, As[cur], 0, k2, w, l);
    BARRIER();
    LGKM0();
    mfma_q<4, 2>(acc, av1, bv1);
    BARRIER();

    // ---- P3: stage Ahi(T+2); Q3 = av0 x bv1; boundary drain ----
    if (st2) stage_half(Ab, As[cur], 128, k2, w, l);
    BARRIER();
    mfma_q<0, 2>(acc, av0, bv1);
    if (st2)      { asm volatile("s_waitcnt vmcnt(4)" ::: "memory"); }
    else if (st1) { asm volatile("s_waitcnt vmcnt(0)" ::: "memory"); }
    BARRIER();
  }

  // ---- epilogue: per-wave LDS bounce -> fully coalesced 16B stores ----
  float bb[4];
  #pragma unroll
  for (int j = 0; j < 4; ++j) bb[j] = bias[bn + wn * 64 + j * 16 + fr];

  u16* eb = (w < 4) ? ((u16*)As + (size_t)w * 8192)
                    : ((u16*)Bs + (size_t)(w - 4) * 8192);   // private 128x64 region
  #pragma unroll
  for (int i = 0; i < 8; ++i)
    #pragma unroll
    for (int j = 0; j < 4; ++j)
      #pragma unroll
      for (int v = 0; v < 4; ++v) {
        const int row = i * 16 + g4 * 4 + v;
        const int col = j * 16 + fr;
        eb[row * 64 + (col ^ ((row & 12) << 2))] = f2bf(acc[i][j][v] + bb[j]);
      }
  LGKM0();                            // own-wave ds_writes visible (private region)
  #pragma unroll
  for (int c = 0; c < 16; ++c) {
    const int lrow = c * 8 + (l >> 3);
    const int lcol = (l & 7) * 8;
    u16x8 d = *(const u16x8*)&eb[lrow * 64 + (lcol ^ ((lrow & 12) << 2))];
    *(u16x8*)&C[(size_t)(bm + wm * 128 + lrow) * N + (bn + wn * 64 + lcol)] = d;
  }
}

// ---------------- scan: elementwise recurrence over t ----------------
template <int OUT_BF16>
__global__ void scan_kernel(const u16* __restrict__ gates,   // [T*B][3H] bf16
                            const float* __restrict__ h0,    // [B][H]
                            const int* __restrict__ L,       // [B]
                            u16* __restrict__ out_bf,        // [T*B][H] bf16
                            float* __restrict__ out_f,       // [T*B][H] f32
                            float* __restrict__ hlast) {     // [B][H]
  const int e = blockIdx.x * blockDim.x + threadIdx.x;       // 0..B*H-1
  const int b = e >> 10;
  const int j = e & 1023;
  float h = h0[e];
  const int Lb = L[b];
  const size_t g0 = (size_t)b * G3 + j;
  const size_t o0 = (size_t)b * H_DIM + j;
  int t = 0;
  #pragma unroll 8
  for (; t < Lb; ++t) {
    const size_t gt = g0 + (size_t)t * (B_DIM * G3);
    float p = bf2f(gates[gt]);
    float q = bf2f(gates[gt + H_DIM]);
    float r = bf2f(gates[gt + 2 * H_DIM]);
    float ii = 1.f / (1.f + __expf(-(p + h)));
    float ff = 1.f / (1.f + __expf(-(q - h)));
    float u  = ii * r + ff * h;
    float e2 = __expf(2.f * u);
    h = 1.f - 2.f / (e2 + 1.f);                 // tanh(u)
    if (OUT_BF16) out_bf[o0 + (size_t)t * (B_DIM * H_DIM)] = f2bf(h);
    else          out_f [o0 + (size_t)t * (B_DIM * H_DIM)] = h;
  }
  const u16 hb = f2bf(h);
  for (; t < T_DIM; ++t) {                      // frozen tail: stores only
    if (OUT_BF16) out_bf[o0 + (size_t)t * (B_DIM * H_DIM)] = hb;
    else          out_f [o0 + (size_t)t * (B_DIM * H_DIM)] = h;
  }
  hlast[o0] = h;
}

extern "C" void kernel_launch(void* const* d_in, const int* in_sizes, int n_in,
                              void* d_out, int out_size, void* d_ws, size_t ws_size,
                              hipStream_t stream) {
  const float* x  = (const float*)d_in[0];
  const float* h0 = (const float*)d_in[1];
  const float* W1 = (const float*)d_in[2];
  const float* b1 = (const float*)d_in[3];
  const float* W2 = (const float*)d_in[4];
  const float* b2 = (const float*)d_in[5];
  const int*   L  = (const int*)d_in[6];

  float* out2 = (float*)d_out;                         // [T][B][H]
  float* hl   = out2 + (size_t)T_DIM * B_DIM * H_DIM;  // h1 [B][H], then h2

  // workspace layout
  char* w = (char*)d_ws;
  u16* xb    = (u16*)(w);                            //  64 MB  x bf16
  u16* W1t   = (u16*)(w + (size_t)67108864);         //   6 MB  W1^T bf16
  u16* W2t   = (u16*)(w + (size_t)73400320);         //   6 MB  W2^T bf16
  u16* gates = (u16*)(w + (size_t)79691776);         // 192 MB  gates bf16 (reused)
  u16* out1  = (u16*)(w + (size_t)281018368);        //  64 MB  out1 bf16

  cast_f32_to_bf16_kernel<<<2048, 256, 0, stream>>>(x, xb, (T_DIM * B_DIM * I_DIM) / 8);
  dim3 tb(32, 8);
  transpose_cast_kernel<<<dim3(G3 / 32, I_DIM / 32), tb, 0, stream>>>(W1, W1t, I_DIM, G3);
  transpose_cast_kernel<<<dim3(G3 / 32, H_DIM / 32), tb, 0, stream>>>(W2, W2t, H_DIM, G3);

  // layer 1
  gemm256_kernel<<<dim3(G3 / 256, M_DIM / 256), 512, 0, stream>>>(
      xb, W1t, b1, gates, G3);
  scan_kernel<1><<<(B_DIM * H_DIM) / 256, 256, 0, stream>>>(
      gates, h0, L, out1, nullptr, hl);

  // layer 2
  gemm256_kernel<<<dim3(G3 / 256, M_DIM / 256), 512, 0, stream>>>(
      out1, W2t, b2, gates, G3);
  scan_kernel<0><<<(B_DIM * H_DIM) / 256, 256, 0, stream>>>(
      gates, h0 + B_DIM * H_DIM, L, nullptr, out2, hl + B_DIM * H_DIM);
}

// Round 8
// 449.612 us; speedup vs baseline: 2.3575x; 1.6181x over previous
//
#include <hip/hip_runtime.h>

#define T_DIM 512
#define B_DIM 64
#define I_DIM 1024
#define H_DIM 1024
#define G3    3072                 // 3*H
#define M_DIM (T_DIM * B_DIM)      // 32768
#define K_DIM 1024
#define KT    16                   // K_DIM / 64

typedef unsigned short u16;
typedef __bf16 bf16x8 __attribute__((ext_vector_type(8)));
typedef float  f32x4  __attribute__((ext_vector_type(4)));
typedef unsigned short u16x8 __attribute__((ext_vector_type(8)));

__device__ __forceinline__ u16 f2bf(float x) {
  union { float f; unsigned u; } v; v.f = x;
  unsigned r = v.u + 0x7fffu + ((v.u >> 16) & 1u);   // RNE
  return (u16)(r >> 16);
}
__device__ __forceinline__ float bf2f(u16 x) {
  union { unsigned u; float f; } v; v.u = ((unsigned)x) << 16;
  return v.f;
}

// ---------- compaction metadata ----------
// meta[0..512] = offset[t] (exclusive prefix of n_t = #{b: L[b]>t}); meta[513]=M_c; meta[514]=M_pad
__global__ void build_offsets_kernel(const int* __restrict__ L, int* __restrict__ meta) {
  __shared__ int cnt[T_DIM];
  __shared__ int Ls[B_DIM];
  const int t = threadIdx.x;                 // 512 threads
  if (t < B_DIM) Ls[t] = L[t];
  __syncthreads();
  int n = 0;
  #pragma unroll 8
  for (int b = 0; b < B_DIM; ++b) n += (Ls[b] > t) ? 1 : 0;
  cnt[t] = n;
  __syncthreads();
  if (t == 0) {
    int acc = 0;
    for (int s = 0; s < T_DIM; ++s) { int c = cnt[s]; cnt[s] = acc; acc += c; }
    meta[T_DIM] = acc;                       // offset[T] = M_c
    meta[513] = acc;
    meta[514] = (acc + 511) & ~511;          // M_pad (512-mult -> active blocks %8==0)
  }
  __syncthreads();
  meta[t] = cnt[t];
}

// crow[t*64+b] = compact row of (t,b) (valid iff t < L[b])
__global__ void build_crow_kernel(const int* __restrict__ L, const int* __restrict__ meta,
                                  int* __restrict__ crow) {
  const int t = blockIdx.x;                  // 512 blocks x 64 threads (1 wave)
  const int b = threadIdx.x;
  const bool valid = t < L[b];
  unsigned long long mask = __ballot(valid);
  const int rank = __popcll(mask & ((1ull << b) - 1ull));
  if (valid) crow[(t << 6) + b] = meta[t] + rank;
}

// ---------- cast+gather x: f32 full layout -> bf16 compact rows ----------
__global__ void cast_gather_kernel(const float* __restrict__ in, const int* __restrict__ L,
                                   const int* __restrict__ crow, u16* __restrict__ out, int n8) {
  int idx = blockIdx.x * blockDim.x + threadIdx.x;
  int stride = gridDim.x * blockDim.x;
  for (int i = idx; i < n8; i += stride) {
    const int row = i >> 7;                  // source row (t*64+b), 128 chunks of 8
    const int ch  = i & 127;
    const int b = row & 63, t = row >> 6;
    if (t >= L[b]) continue;
    const int cr = crow[row];
    const float4* p = (const float4*)(in + (size_t)row * 1024 + ch * 8);
    float4 a = p[0], bb = p[1];
    u16x8 o;
    o[0] = f2bf(a.x);  o[1] = f2bf(a.y);  o[2] = f2bf(a.z);  o[3] = f2bf(a.w);
    o[4] = f2bf(bb.x); o[5] = f2bf(bb.y); o[6] = f2bf(bb.z); o[7] = f2bf(bb.w);
    *(u16x8*)(out + (size_t)cr * 1024 + ch * 8) = o;
  }
}

// ------------- transpose-cast W[K][N] f32 -> Wt[N][K] bf16 -------------
__global__ void transpose_cast_kernel(const float* __restrict__ W,
                                      u16* __restrict__ Wt, int K, int N) {
  __shared__ float tile[32][33];
  int n0 = blockIdx.x * 32, k0 = blockIdx.y * 32;
  int tx = threadIdx.x, ty = threadIdx.y;   // blockDim = (32,8)
  #pragma unroll
  for (int dy = 0; dy < 32; dy += 8)
    tile[ty + dy][tx] = W[(size_t)(k0 + ty + dy) * N + n0 + tx];
  __syncthreads();
  #pragma unroll
  for (int dy = 0; dy < 32; dy += 8)
    Wt[(size_t)(n0 + ty + dy) * K + k0 + tx] = f2bf(tile[tx][ty + dy]);
}

// === 256x256 GEMM (R5 schedule: 2 barriers/K-tile, MFMA-shadowed ds_reads) ===
__device__ __forceinline__ void gload_lds16(const void* g, void* l) {
  __builtin_amdgcn_global_load_lds(
      (const __attribute__((address_space(1))) void*)g,
      (__attribute__((address_space(3))) void*)l, 16, 0, 0);
}

__device__ __forceinline__ void stage_half(const u16* __restrict__ G, u16* lbuf,
                                           int rb, int k0, int w, int l) {
  const int cs   = (l & 7) ^ (l >> 3);
  const int rsub = l >> 3;
  #pragma unroll
  for (int r = 0; r < 2; ++r) {
    const int row0 = rb + r * 64 + w * 8;
    gload_lds16(G + (size_t)(row0 + rsub) * K_DIM + k0 + cs * 8,
                lbuf + (size_t)row0 * 64);
  }
}

__device__ __forceinline__ bf16x8 ldfrag(const u16* buf, int row, int ks, int fr, int g4) {
  const int slot = ((ks << 2) + g4) ^ (fr & 7);
  return *(const bf16x8*)(buf + (size_t)row * 64 + slot * 8);
}

__device__ __forceinline__ void read_a(const u16* buf, bf16x8 (&dst)[4][2],
                                       int rbase, int fr, int g4) {
  #pragma unroll
  for (int m = 0; m < 4; ++m) {
    dst[m][0] = ldfrag(buf, rbase + m * 16 + fr, 0, fr, g4);
    dst[m][1] = ldfrag(buf, rbase + m * 16 + fr, 1, fr, g4);
  }
}
__device__ __forceinline__ void read_b(const u16* buf, bf16x8 (&dst)[2][2],
                                       int rbase, int fr, int g4) {
  #pragma unroll
  for (int n = 0; n < 2; ++n) {
    dst[n][0] = ldfrag(buf, rbase + n * 16 + fr, 0, fr, g4);
    dst[n][1] = ldfrag(buf, rbase + n * 16 + fr, 1, fr, g4);
  }
}

#define BARRIER()  do { __builtin_amdgcn_s_barrier(); __builtin_amdgcn_sched_barrier(0); } while (0)
#define LGKM0()    do { asm volatile("s_waitcnt lgkmcnt(0)" ::: "memory"); __builtin_amdgcn_sched_barrier(0); } while (0)

#define MFMA_Q(ACC, AV, BV)                                                            \
  do {                                                                                 \
    __builtin_amdgcn_s_setprio(1);                                                     \
    _Pragma("unroll")                                                                  \
    for (int m = 0; m < 4; ++m)                                                        \
      _Pragma("unroll")                                                                \
      for (int n = 0; n < 2; ++n) {                                                    \
        ACC = __builtin_amdgcn_mfma_f32_16x16x32_bf16(AV[m][0], BV[n][0], ACC, 0, 0, 0); \
        ACC = __builtin_amdgcn_mfma_f32_16x16x32_bf16(AV[m][1], BV[n][1], ACC, 0, 0, 0); \
      }                                                                                \
    __builtin_amdgcn_s_setprio(0);                                                     \
  } while (0)

__global__ __launch_bounds__(512, 2) void gemm256_kernel(
    const u16* __restrict__ A, const u16* __restrict__ Bt,
    const float* __restrict__ bias, u16* __restrict__ C, int N,
    const int* __restrict__ meta) {
  __shared__ u16 As[2][256 * 64];
  __shared__ u16 Bs[2][256 * 64];
  const int tid = threadIdx.x;
  const int l  = tid & 63, w = tid >> 6;
  const int wm = w >> 2,  wn = w & 3;
  const int fr = l & 15,  g4 = l >> 4;

  // active-grid XCD swizzle: only ny = M_pad/256 y-blocks have work (ny even)
  const int ny   = meta[514] >> 8;
  const int nact = gridDim.x * ny;
  const int q    = nact >> 3;
  const int lin  = blockIdx.y * gridDim.x + blockIdx.x;
  const int idx  = lin >> 3;
  if (idx >= q) return;
  const int swz = (lin & 7) * q + idx;
  const int bx = swz % gridDim.x, by = swz / gridDim.x;
  const int bm = by * 256, bn = bx * 256;

  const u16* Ab = A  + (size_t)bm * K_DIM;
  const u16* Bb = Bt + (size_t)bn * K_DIM;

  // prologue: tile0 fully + tile1 {A-lo, A-hi, B-lo}  (14 loads/thread)
  stage_half(Ab, As[0], 0,   0,  w, l);
  stage_half(Ab, As[0], 128, 0,  w, l);
  stage_half(Bb, Bs[0], 0,   0,  w, l);
  stage_half(Bb, Bs[0], 128, 0,  w, l);
  stage_half(Ab, As[1], 0,   64, w, l);
  stage_half(Ab, As[1], 128, 64, w, l);
  stage_half(Bb, Bs[1], 0,   64, w, l);

  f32x4 acc[8][4] = {};
  bf16x8 av0[4][2], av1[4][2], bv0[2][2], bv1[2][2];

  // ---- main loop: tiles 0..KT-2 ----
  for (int T = 0; T < KT - 1; ++T) {
    const u16* Ac = As[T & 1];
    const u16* Bc = Bs[T & 1];
    u16* Bn1 = Bs[(T + 1) & 1];
    u16* An2 = As[T & 1];        u16* Bn2 = Bs[T & 1];   // tile T+2 parity == T
    const int k1 = (T + 1) * 64, k2 = (T + 2) * 64;
    const bool st2 = (T + 2) < KT;

    asm volatile("s_waitcnt vmcnt(6)" ::: "memory");
    BARRIER();                     // tile T resident; tile T-1 reads all consumed

    read_a(Ac, av0, wm * 128, fr, g4);
    read_b(Bc, bv0, wn * 64, fr, g4);
    stage_half(Bb, Bn1, 128, k1, w, l);
    LGKM0();

    MFMA_Q(acc[m][n], av0, bv0);
    read_b(Bc, bv1, wn * 64 + 32, fr, g4);
    LGKM0();

    MFMA_Q(acc[m][n + 2], av0, bv1);
    read_a(Ac, av1, wm * 128 + 64, fr, g4);
    LGKM0();
    BARRIER();                     // all waves' tile-T LDS reads complete

    if (st2) {
      stage_half(Ab, An2, 0,   k2, w, l);
      stage_half(Ab, An2, 128, k2, w, l);
      stage_half(Bb, Bn2, 0,   k2, w, l);
    }

    MFMA_Q(acc[m + 4][n + 2], av1, bv1);
    MFMA_Q(acc[m + 4][n],     av1, bv0);
  }

  // ---- peeled final tile (T = KT-1) ----
  {
    const u16* Ac = As[(KT - 1) & 1];
    const u16* Bc = Bs[(KT - 1) & 1];
    asm volatile("s_waitcnt vmcnt(0)" ::: "memory");
    BARRIER();
    #pragma unroll
    for (int m = 0; m < 4; ++m) {
      av0[m][0] = ldfrag(Ac, wm * 128 + m * 16 + fr, 0, fr, g4);
      av0[m][1] = ldfrag(Ac, wm * 128 + m * 16 + fr, 1, fr, g4);
      av1[m][0] = ldfrag(Ac, wm * 128 + (m + 4) * 16 + fr, 0, fr, g4);
      av1[m][1] = ldfrag(Ac, wm * 128 + (m + 4) * 16 + fr, 1, fr, g4);
    }
    #pragma unroll
    for (int n = 0; n < 2; ++n) {
      bv0[n][0] = ldfrag(Bc, wn * 64 + n * 16 + fr, 0, fr, g4);
      bv0[n][1] = ldfrag(Bc, wn * 64 + n * 16 + fr, 1, fr, g4);
      bv1[n][0] = ldfrag(Bc, wn * 64 + (n + 2) * 16 + fr, 0, fr, g4);
      bv1[n][1] = ldfrag(Bc, wn * 64 + (n + 2) * 16 + fr, 1, fr, g4);
    }
    LGKM0();
    MFMA_Q(acc[m][n],         av0, bv0);
    MFMA_Q(acc[m][n + 2],     av0, bv1);
    MFMA_Q(acc[m + 4][n + 2], av1, bv1);
    MFMA_Q(acc[m + 4][n],     av1, bv0);
    BARRIER();                     // all LDS reads done -> LDS reusable
  }

  // ---- epilogue: per-wave LDS bounce -> fully coalesced 16B stores ----
  float bb[4];
  #pragma unroll
  for (int j = 0; j < 4; ++j) bb[j] = bias[bn + wn * 64 + j * 16 + fr];

  u16* eb = (w < 4) ? ((u16*)As + (size_t)w * 8192)
                    : ((u16*)Bs + (size_t)(w - 4) * 8192);
  #pragma unroll
  for (int i = 0; i < 8; ++i)
    #pragma unroll
    for (int j = 0; j < 4; ++j)
      #pragma unroll
      for (int v = 0; v < 4; ++v) {
        const int row = i * 16 + g4 * 4 + v;
        const int col = j * 16 + fr;
        eb[row * 64 + (col ^ ((row & 12) << 2))] = f2bf(acc[i][j][v] + bb[j]);
      }
  LGKM0();
  #pragma unroll
  for (int c = 0; c < 16; ++c) {
    const int lrow = c * 8 + (l >> 3);
    const int lcol = (l & 7) * 8;
    u16x8 d = *(const u16x8*)&eb[lrow * 64 + (lcol ^ ((lrow & 12) << 2))];
    *(u16x8*)&C[(size_t)(bm + wm * 128 + lrow) * N + (bn + wn * 64 + lcol)] = d;
  }
}

// ---------------- scan: elementwise recurrence over t (compact gates) ----------------
template <int OUT_BF16>
__global__ void scan_kernel(const u16* __restrict__ gates,   // [M_c][3H] bf16 compact
                            const float* __restrict__ h0,    // [B][H]
                            const int* __restrict__ L,       // [B]
                            const int* __restrict__ crow,    // [T*B] compact row map
                            u16* __restrict__ out_bf,        // [M_c][H] bf16 compact
                            float* __restrict__ out_f,       // [T*B][H] f32 full
                            float* __restrict__ hlast) {     // [B][H]
  const int e = blockIdx.x * blockDim.x + threadIdx.x;       // 0..B*H-1
  const int b = e >> 10;
  const int j = e & 1023;
  float h = h0[e];
  const int Lb = L[b];
  const size_t o0 = (size_t)b * H_DIM + j;
  int t = 0;
  #pragma unroll 8
  for (; t < Lb; ++t) {
    const int cr = crow[(t << 6) + b];
    const size_t gt = (size_t)cr * G3 + j;
    float p = bf2f(gates[gt]);
    float q = bf2f(gates[gt + H_DIM]);
    float r = bf2f(gates[gt + 2 * H_DIM]);
    float ii = 1.f / (1.f + __expf(-(p + h)));
    float ff = 1.f / (1.f + __expf(-(q - h)));
    float u  = ii * r + ff * h;
    float e2 = __expf(2.f * u);
    h = 1.f - 2.f / (e2 + 1.f);                 // tanh(u)
    if (OUT_BF16) out_bf[(size_t)cr * H_DIM + j] = f2bf(h);   // compact (layer-2 input)
    else          out_f [o0 + (size_t)t * (B_DIM * H_DIM)] = h;
  }
  if (!OUT_BF16) {
    for (; t < T_DIM; ++t)                      // frozen tail: stores only
      out_f[o0 + (size_t)t * (B_DIM * H_DIM)] = h;
  }
  hlast[o0] = h;
}

extern "C" void kernel_launch(void* const* d_in, const int* in_sizes, int n_in,
                              void* d_out, int out_size, void* d_ws, size_t ws_size,
                              hipStream_t stream) {
  const float* x  = (const float*)d_in[0];
  const float* h0 = (const float*)d_in[1];
  const float* W1 = (const float*)d_in[2];
  const float* b1 = (const float*)d_in[3];
  const float* W2 = (const float*)d_in[4];
  const float* b2 = (const float*)d_in[5];
  const int*   L  = (const int*)d_in[6];

  float* out2 = (float*)d_out;                         // [T][B][H]
  float* hl   = out2 + (size_t)T_DIM * B_DIM * H_DIM;  // h1 [B][H], then h2

  // workspace layout
  char* w = (char*)d_ws;
  u16* xb    = (u16*)(w);                            //  64 MB  x bf16 (compact)
  u16* W1t   = (u16*)(w + (size_t)67108864);         //   6 MB  W1^T bf16
  u16* W2t   = (u16*)(w + (size_t)73400320);         //   6 MB  W2^T bf16
  u16* gates = (u16*)(w + (size_t)79691776);         // 192 MB  gates bf16 (compact, reused)
  u16* out1  = (u16*)(w + (size_t)281018368);        //  64 MB  out1 bf16 (compact)
  int* meta  = (int*)(w + (size_t)348127232);        // offset[513] + M_c + M_pad
  int* crow  = (int*)(w + (size_t)348131328);        // [T*B] int

  build_offsets_kernel<<<1, 512, 0, stream>>>(L, meta);
  build_crow_kernel<<<T_DIM, 64, 0, stream>>>(L, meta, crow);
  cast_gather_kernel<<<2048, 256, 0, stream>>>(x, L, crow, xb, (T_DIM * B_DIM * I_DIM) / 8);
  dim3 tb(32, 8);
  transpose_cast_kernel<<<dim3(G3 / 32, I_DIM / 32), tb, 0, stream>>>(W1, W1t, I_DIM, G3);
  transpose_cast_kernel<<<dim3(G3 / 32, H_DIM / 32), tb, 0, stream>>>(W2, W2t, H_DIM, G3);

  // layer 1 (GEMM over compact rows only; blocks beyond M_pad exit)
  gemm256_kernel<<<dim3(G3 / 256, M_DIM / 256), 512, 0, stream>>>(
      xb, W1t, b1, gates, G3, meta);
  scan_kernel<1><<<(B_DIM * H_DIM) / 256, 256, 0, stream>>>(
      gates, h0, L, crow, out1, nullptr, hl);

  // layer 2
  gemm256_kernel<<<dim3(G3 / 256, M_DIM / 256), 512, 0, stream>>>(
      out1, W2t, b2, gates, G3, meta);
  scan_kernel<0><<<(B_DIM * H_DIM) / 256, 256, 0, stream>>>(
      gates, h0 + B_DIM * H_DIM, L, crow, nullptr, out2, hl + B_DIM * H_DIM);
}